// Round 16
// baseline (60.299 us; speedup 1.0000x reference)
//
#include <hip/hip_runtime.h>
#include <hip/hip_bf16.h>
#include <math.h>

#define N 384
#define D 256
#define R 64
#define RELH 128
#define NN (N*N)
#define ND (N*D)
#define JCHUNK 64
#define NCHUNK (N / JCHUNK)   // 6
#define TPB 16                // legacy tt pairs per block (fallback)
#define LOG2E 1.44269504088896f
#define HS_STRIDE 264         // 256 + 8 fp16 pad

typedef _Float16 f16x8 __attribute__((ext_vector_type(8)));
typedef _Float16 f16x4 __attribute__((ext_vector_type(4)));
typedef _Float16 f16x2 __attribute__((ext_vector_type(2)));
typedef float f32x4 __attribute__((ext_vector_type(4)));

__device__ __forceinline__ float fast_sigmoid(float x) {
    float e = __builtin_amdgcn_exp2f(-LOG2E * x);
    return __builtin_amdgcn_rcpf(1.f + e);
}
__device__ __forceinline__ float fast_exp(float x) {
    return __builtin_amdgcn_exp2f(LOG2E * x);
}
__device__ __forceinline__ float fast_tanh(float x) {
    float e = __builtin_amdgcn_exp2f(2.f * LOG2E * x);
    return 1.f - 2.f * __builtin_amdgcn_rcpf(1.f + e);
}

// ---------------------------------------------------------------------------
// prep_kernel: role-switched on blockIdx.x (79 blocks x 256 threads)
//  [0,6):   u/v wave reductions
//  [6,54):  [A+ngate_b | Bm] = self_h @ ngate_w[64:576] via fp16 MFMA;
//           Bm packed with self_h into bh (fp16x2)
//  [54,62): wf  = fragment-ordered fp16 ngate_w[0:64,:]
//  [62,78): wf1/wf2 = fragment-ordered fp16 wnei_w1 / wnei_w2
//  [78]:    wfr = fragment-ordered fp16 rel_w2 (128x64)
// ---------------------------------------------------------------------------
__global__ __launch_bounds__(256) void prep_kernel(
        const float* __restrict__ self_h, const float* __restrict__ ngate_w,
        const float* __restrict__ ngate_b, const float* __restrict__ war_w,
        const float* __restrict__ wnei_w1, const float* __restrict__ wnei_w2,
        const float* __restrict__ rel_w2,
        float* __restrict__ A, float* __restrict__ Bm,
        unsigned int* __restrict__ bh,
        float* __restrict__ u, float* __restrict__ v,
        _Float16* __restrict__ wf,
        _Float16* __restrict__ wf1, _Float16* __restrict__ wf2,
        _Float16* __restrict__ wfr) {
    int b = blockIdx.x, tid = threadIdx.x;
    int wv = tid >> 6, l = tid & 63;
    int lg = l >> 4, ln = l & 15;

    if (b < 6) {
        int r0 = b * 64 + wv * 16;
        for (int rr = 0; rr < 16; ++rr) {
            int row = r0 + rr;
            float su = 0.f, sv = 0.f;
            #pragma unroll
            for (int k = 0; k < 4; ++k) {
                int d = k * 64 + l;
                float h = self_h[row * D + d];
                su = fmaf(h, war_w[R + d], su);
                sv = fmaf(h, war_w[R + D + d], sv);
            }
            #pragma unroll
            for (int off = 32; off; off >>= 1) {
                su += __shfl_down(su, off);
                sv += __shfl_down(sv, off);
            }
            if (l == 0) { u[row] = su; v[row] = sv; }
        }
    } else if (b < 54) {
        int W = (b - 6) * 4 + wv;        // 0..191
        int m0 = (W >> 3) * 16;          // row block
        int cb = (W & 7) * 64;           // col base in [0,512)
        const float* wsrc = ngate_w + (size_t)(cb >= 256 ? 320 : 64) * D + (cb & 255);
        f32x4 acc[4];
        #pragma unroll
        for (int nt = 0; nt < 4; ++nt) acc[nt] = (f32x4){0.f, 0.f, 0.f, 0.f};
        #pragma unroll
        for (int s = 0; s < 8; ++s) {
            const float4* hp = (const float4*)&self_h[(size_t)(m0 + ln) * D + s * 32 + lg * 8];
            float4 h0 = hp[0], h1 = hp[1];
            f16x8 af;
            af[0] = (_Float16)h0.x; af[1] = (_Float16)h0.y;
            af[2] = (_Float16)h0.z; af[3] = (_Float16)h0.w;
            af[4] = (_Float16)h1.x; af[5] = (_Float16)h1.y;
            af[6] = (_Float16)h1.z; af[7] = (_Float16)h1.w;
            #pragma unroll
            for (int nt = 0; nt < 4; ++nt) {
                f16x8 bf;
                #pragma unroll
                for (int ii = 0; ii < 8; ++ii)
                    bf[ii] = (_Float16)wsrc[(size_t)(s * 32 + lg * 8 + ii) * D + nt * 16 + ln];
                acc[nt] = __builtin_amdgcn_mfma_f32_16x16x32_f16(af, bf, acc[nt], 0, 0, 0);
            }
        }
        #pragma unroll
        for (int nt = 0; nt < 4; ++nt)
            #pragma unroll
            for (int reg = 0; reg < 4; ++reg) {
                int row = m0 + lg * 4 + reg;
                int col = cb + nt * 16 + ln;
                if (col < 256) {
                    A[row * D + col] = acc[nt][reg] + ngate_b[col];
                } else {
                    int c2 = col - 256;
                    float bmv = acc[nt][reg];
                    Bm[row * D + c2] = bmv;                 // fallback path
                    f16x2 pk;
                    pk[0] = (_Float16)bmv;
                    pk[1] = (_Float16)self_h[row * D + c2];
                    bh[row * D + c2] = __builtin_bit_cast(unsigned int, pk);
                }
            }
    } else if (b < 62) {
        int blkEq = (b - 54) * 4 + wv;   // 0..31
        int s = blkEq >> 4, t = blkEq & 15;
        #pragma unroll
        for (int ii = 0; ii < 8; ++ii) {
            float w = ngate_w[(s * 32 + lg * 8 + ii) * D + t * 16 + ln];
            wf[((size_t)(s * 16 + t) * 64 + l) * 8 + ii] = (_Float16)w;
        }
    } else if (b < 78) {
        int base = ((b - 62) * 4 + wv) * 4;   // tile base in [0,256)
        #pragma unroll
        for (int k = 0; k < 4; ++k) {
            int T = base + k;
            int mat = T >> 7, rem = T & 127;
            int s = rem >> 4, t = rem & 15;
            const float* wsrc = mat ? wnei_w2 : wnei_w1;
            _Float16* dst = mat ? wf2 : wf1;
            #pragma unroll
            for (int ii = 0; ii < 8; ++ii) {
                float w = wsrc[(size_t)(s * 32 + lg * 8 + ii) * D + t * 16 + ln];
                dst[((size_t)(s * 16 + t) * 64 + l) * 8 + ii] = (_Float16)w;
            }
        }
    } else {
        // wfr: rel_w2 [128x64] fragments; 16 tiles (s 0..3, nt 0..3)
        #pragma unroll
        for (int k = 0; k < 4; ++k) {
            int T = wv * 4 + k;
            int s = T >> 2, nt = T & 3;
            #pragma unroll
            for (int ii = 0; ii < 8; ++ii) {
                float w = rel_w2[(size_t)(s * 32 + lg * 8 + ii) * R + nt * 16 + ln];
                wfr[((size_t)(s * 4 + nt) * 64 + l) * 8 + ii] = (_Float16)w;
            }
        }
    }
}

// ---------------------------------------------------------------------------
// fused_kernel v5 (transposed MFMAs): one block per row i, 256 thr = 4 waves.
// All gate MFMAs computed as L^T = W^T @ r^T (operands swapped) so the
// D-fragment row index = d/rcol and col index = j. This makes bh loads
// uint4 (4 consecutive d per thread), p=ttrow[j] one read per jt, r-writes
// ds_write_b64, and based/hsum float4.
// ---------------------------------------------------------------------------
__global__ __launch_bounds__(256) void fused_kernel(
        const float* __restrict__ corr,
        const float* __restrict__ rel_w1, const float* __restrict__ rel_b1,
        const float* __restrict__ rel_b2,
        const float* __restrict__ war_w, const float* __restrict__ v,
        const int* __restrict__ nei,
        const _Float16* __restrict__ wfr, const _Float16* __restrict__ wf,
        const float* __restrict__ A, const unsigned int* __restrict__ bh,
        float* __restrict__ hsum) {
    __shared__ __align__(16) _Float16 rlds[N * R];   // 48 KB, swizzled
    __shared__ float ttrow[N];
    __shared__ float red[4];
    __shared__ float sM, sS;
    int i = blockIdx.x, tid = threadIdx.x;
    int wv = tid >> 6, l = tid & 63;
    int lg = l >> 4, ln = l & 15;
    char* rbase = (char*)rlds;

    // ---- phase 1: 6 j-tiles per wave; r^T = W2^T @ H1^T via swapped MFMA ----
    {
        float w10[4][8], w11[4][8], b1v[4][8];
        #pragma unroll
        for (int s = 0; s < 4; ++s)
            #pragma unroll
            for (int ii = 0; ii < 8; ++ii) {
                int hk = s * 32 + lg * 8 + ii;
                w10[s][ii] = rel_w1[hk];
                w11[s][ii] = rel_w1[RELH + hk];
                b1v[s][ii] = rel_b1[hk];
            }
        f32x4 b2q[4], warwq[4];
        #pragma unroll
        for (int nt = 0; nt < 4; ++nt) {
            b2q[nt]   = *(const f32x4*)&rel_b2[nt * 16 + lg * 4];
            warwq[nt] = *(const f32x4*)&war_w[nt * 16 + lg * 4];
        }

        #pragma unroll
        for (int t = 0; t < 6; ++t) {
            int j0 = (wv * 6 + t) * 16;
            float2 x = ((const float2*)corr)[(size_t)i * N + j0 + ln];
            f16x8 af[4];
            #pragma unroll
            for (int s = 0; s < 4; ++s)
                #pragma unroll
                for (int ii = 0; ii < 8; ++ii) {
                    float h = fmaxf(0.f, fmaf(x.y, w11[s][ii], fmaf(x.x, w10[s][ii], b1v[s][ii])));
                    af[s][ii] = (_Float16)h;
                }
            f32x4 c[4];
            #pragma unroll
            for (int nt = 0; nt < 4; ++nt) c[nt] = (f32x4){0.f, 0.f, 0.f, 0.f};
            #pragma unroll
            for (int nt = 0; nt < 4; ++nt)
                #pragma unroll
                for (int s = 0; s < 4; ++s) {
                    f16x8 bfv = *(const f16x8*)&wfr[((size_t)(s * 4 + nt) * 64 + l) * 8];
                    // swapped: A = W2^T frag, B = H1^T frag
                    c[nt] = __builtin_amdgcn_mfma_f32_16x16x32_f16(bfv, af[s], c[nt], 0, 0, 0);
                }
            // c[nt][reg] = r[j=j0+ln][rcol = nt*16 + lg*4 + reg]
            int lj = j0 + ln;
            float tpart = 0.f;
            #pragma unroll
            for (int nt = 0; nt < 4; ++nt) {
                f16x4 pk;
                #pragma unroll
                for (int reg = 0; reg < 4; ++reg) {
                    float rv = fmaxf(0.f, c[nt][reg] + b2q[nt][reg]);
                    pk[reg] = (_Float16)rv;
                    tpart = fmaf(rv, warwq[nt][reg], tpart);
                }
                int off = (lj * 128 + (nt * 16 + lg * 4) * 2) ^ ((lj & 7) << 4);
                *(f16x4*)(rbase + off) = pk;
            }
            tpart += __shfl_xor(tpart, 16);
            tpart += __shfl_xor(tpart, 32);
            if (lg == 0) ttrow[lj] = tpart + v[lj];
        }
    }
    __syncthreads();

    // ---- phase 2: softmax over ttrow[0..383] ----
    {
        float tv1 = ttrow[tid];
        bool va1 = (nei[(size_t)i * N + tid] > 0) && (tv1 != 0.f);
        float tv2 = 0.f; bool va2 = false;
        if (tid < N - 256) {
            tv2 = ttrow[tid + 256];
            va2 = (nei[(size_t)i * N + tid + 256] > 0) && (tv2 != 0.f);
        }
        float m = va1 ? tv1 : -INFINITY;
        if (va2) m = fmaxf(m, tv2);
        #pragma unroll
        for (int off = 32; off; off >>= 1) m = fmaxf(m, __shfl_down(m, off));
        if (l == 0) red[wv] = m;
        __syncthreads();
        if (tid == 0) sM = fmaxf(fmaxf(red[0], red[1]), fmaxf(red[2], red[3]));
        __syncthreads();
        float M = sM;
        float e1 = 0.f, e2 = 0.f;
        if (M != -INFINITY) {
            if (va1) e1 = fast_exp(tv1 - M);
            if (va2) e2 = fast_exp(tv2 - M);
        }
        float sum = e1 + e2;
        #pragma unroll
        for (int off = 32; off; off >>= 1) sum += __shfl_down(sum, off);
        if (l == 0) red[wv] = sum;
        __syncthreads();
        if (tid == 0) sS = red[0] + red[1] + red[2] + red[3];
        __syncthreads();
        float rden = (sS > 0.f) ? __builtin_amdgcn_rcpf(sS) : 0.f;
        ttrow[tid] = va1 ? e1 * rden : 0.f;
        if (tid < N - 256) ttrow[tid + 256] = va2 ? e2 * rden : 0.f;
    }
    __syncthreads();

    // ---- phase 3: gate via L^T = W^T @ r^T; wave wv owns d-cols
    //      [wv*64,(wv+1)*64); thread owns d = wv*64 + dt*16 + lg*4 + reg,
    //      j = jt*16 + ln.
    f16x8 bf[2][4];
    #pragma unroll
    for (int s = 0; s < 2; ++s)
        #pragma unroll
        for (int dt = 0; dt < 4; ++dt)
            bf[s][dt] = *(const f16x8*)&wf[((size_t)(s * 16 + wv * 4 + dt) * 64 + l) * 8];
    f32x4 based4[4];
    #pragma unroll
    for (int dt = 0; dt < 4; ++dt)
        based4[dt] = *(const f32x4*)&A[i * D + wv * 64 + dt * 16 + lg * 4];

    f32x4 acc[4];
    #pragma unroll
    for (int dt = 0; dt < 4; ++dt) acc[dt] = (f32x4){0.f, 0.f, 0.f, 0.f};

    for (int jt = 0; jt < 24; ++jt) {
        int jj = jt * 16 + ln;
        float p = ttrow[jj];
        f16x8 afr[2];
        #pragma unroll
        for (int s = 0; s < 2; ++s) {
            int off = (jj * 128 + (s * 64 + lg * 16)) ^ ((jj & 7) << 4);
            afr[s] = *(const f16x8*)(rbase + off);
        }
        f32x4 c[4];
        #pragma unroll
        for (int dt = 0; dt < 4; ++dt) c[dt] = (f32x4){0.f, 0.f, 0.f, 0.f};
        #pragma unroll
        for (int dt = 0; dt < 4; ++dt)
            #pragma unroll
            for (int s = 0; s < 2; ++s)
                c[dt] = __builtin_amdgcn_mfma_f32_16x16x32_f16(bf[s][dt], afr[s], c[dt], 0, 0, 0);
        #pragma unroll
        for (int dt = 0; dt < 4; ++dt) {
            uint4 uu = *(const uint4*)&bh[(size_t)jj * D + wv * 64 + dt * 16 + lg * 4];
            unsigned int uc[4] = {uu.x, uu.y, uu.z, uu.w};
            #pragma unroll
            for (int reg = 0; reg < 4; ++reg) {
                f16x2 bhv = __builtin_bit_cast(f16x2, uc[reg]);
                float logit = c[dt][reg] + based4[dt][reg] + (float)bhv[0];
                float g = fast_sigmoid(logit);
                acc[dt][reg] = fmaf(p * g, (float)bhv[1], acc[dt][reg]);
            }
        }
    }
    // reduce over the 16 ln-lanes (different j, same d)
    #pragma unroll
    for (int dt = 0; dt < 4; ++dt)
        #pragma unroll
        for (int reg = 0; reg < 4; ++reg) {
            float a = acc[dt][reg];
            a += __shfl_xor(a, 1);
            a += __shfl_xor(a, 2);
            a += __shfl_xor(a, 4);
            a += __shfl_xor(a, 8);
            acc[dt][reg] = a;
        }
    if (ln == 0) {
        #pragma unroll
        for (int dt = 0; dt < 4; ++dt)
            *(f32x4*)&hsum[(size_t)i * D + wv * 64 + dt * 16 + lg * 4] = acc[dt];
    }
}

// ---------------------------------------------------------------------------
// Fallback VALU tt.
// ---------------------------------------------------------------------------
__global__ __launch_bounds__(256) void tt_valu_kernel(
        const float* __restrict__ corr,
        const float* __restrict__ rel_w1, const float* __restrict__ rel_b1,
        const float* __restrict__ rel_w2, const float* __restrict__ rel_b2,
        const float* __restrict__ war_w, const float* __restrict__ war_b,
        const float* __restrict__ u, const float* __restrict__ v,
        float* __restrict__ tt) {
    __shared__ __align__(16) float h1s[4][RELH];
    int tid = threadIdx.x, w = tid >> 6, l = tid & 63;
    float w1a0 = rel_w1[l],      w1a1 = rel_w1[RELH + l];
    float w1b0 = rel_w1[64 + l], w1b1 = rel_w1[RELH + 64 + l];
    float b1a = rel_b1[l], b1b = rel_b1[64 + l];
    float b2v = rel_b2[l], warw = war_w[l], wb = war_b[0];
    int pbase = blockIdx.x * TPB;
    #pragma unroll
    for (int it = 0; it < TPB / 4; ++it) {
        int p = pbase + it * 4 + w;
        int i = p / N, j = p - i * N;
        float2 x = *(const float2*)(corr + p * 2);
        h1s[w][l]      = fmaxf(0.f, fmaf(x.y, w1a1, fmaf(x.x, w1a0, b1a)));
        h1s[w][l + 64] = fmaxf(0.f, fmaf(x.y, w1b1, fmaf(x.x, w1b0, b1b)));
        float c0 = b2v, c1 = 0.f, c2 = 0.f, c3 = 0.f;
        const float4* hv = (const float4*)h1s[w];
        #pragma unroll
        for (int k4 = 0; k4 < RELH / 4; ++k4) {
            float4 h = hv[k4];
            c0 = fmaf(h.x, rel_w2[(k4 * 4 + 0) * R + l], c0);
            c1 = fmaf(h.y, rel_w2[(k4 * 4 + 1) * R + l], c1);
            c2 = fmaf(h.z, rel_w2[(k4 * 4 + 2) * R + l], c2);
            c3 = fmaf(h.w, rel_w2[(k4 * 4 + 3) * R + l], c3);
        }
        float rm = fmaxf(0.f, (c0 + c1) + (c2 + c3));
        float part = rm * warw;
        for (int off = 32; off; off >>= 1) part += __shfl_down(part, off);
        if (l == 0) tt[p] = part + u[i] + v[j] + wb;
    }
}

// ---------------------------------------------------------------------------
// Fallback row softmax.
// ---------------------------------------------------------------------------
__global__ void softmax_kernel(const float* __restrict__ tt,
                               const int* __restrict__ nei,
                               float* __restrict__ pos) {
    __shared__ float red[4];
    __shared__ float sM, sS;
    int i = blockIdx.x, tid = threadIdx.x;
    float tv[2]; bool valid[2];
    float m = -INFINITY;
    for (int s = 0; s < 2; ++s) {
        int j = tid + s * 256;
        valid[s] = false; tv[s] = 0.f;
        if (j < N) {
            float t = tt[i * N + j];
            bool va = (nei[i * N + j] > 0) && (t != 0.f);
            tv[s] = t; valid[s] = va;
            if (va) m = fmaxf(m, t);
        }
    }
    for (int off = 32; off; off >>= 1) m = fmaxf(m, __shfl_down(m, off));
    if ((tid & 63) == 0) red[tid >> 6] = m;
    __syncthreads();
    if (tid == 0) sM = fmaxf(fmaxf(red[0], red[1]), fmaxf(red[2], red[3]));
    __syncthreads();
    float M = sM;
    float e[2] = {0.f, 0.f};
    float sum = 0.f;
    if (M != -INFINITY) {
        for (int s = 0; s < 2; ++s)
            if (valid[s]) { e[s] = fast_exp(tv[s] - M); sum += e[s]; }
    }
    for (int off = 32; off; off >>= 1) sum += __shfl_down(sum, off);
    if ((tid & 63) == 0) red[tid >> 6] = sum;
    __syncthreads();
    if (tid == 0) sS = red[0] + red[1] + red[2] + red[3];
    __syncthreads();
    float rden = (sS > 0.f) ? __builtin_amdgcn_rcpf(sS) : 0.f;
    for (int s = 0; s < 2; ++s) {
        int j = tid + s * 256;
        if (j < N) pos[i * N + j] = valid[s] ? e[s] * rden : 0.f;
    }
}

// ---------------------------------------------------------------------------
// Fallback gate (no workspace for fused path).
// ---------------------------------------------------------------------------
__global__ void gate_norc_kernel(const float* __restrict__ corr,
                            const float* __restrict__ rel_w1, const float* __restrict__ rel_b1,
                            const float* __restrict__ rel_w2, const float* __restrict__ rel_b2,
                            const float* __restrict__ ngate_w,
                            const float* __restrict__ A, const float* __restrict__ Bm,
                            const float* __restrict__ pos, const float* __restrict__ self_h,
                            float* __restrict__ partial) {
    __shared__ __align__(16) float h1[4][RELH];
    __shared__ __align__(16) float rs[4][R];
    __shared__ float wsh[4];
    int i = blockIdx.x, tid = threadIdx.x;
    int jbase = blockIdx.y * JCHUNK;
    int w = tid >> 6, l = tid & 63;
    ((float*)rs)[tid] = 0.f;
    float base = A[i * D + tid];
    float acc = 0.f;
    for (int j0 = jbase; j0 < jbase + JCHUNK; j0 += 4) {
        int j = j0 + w;
        int p = i * N + j;
        float wt = pos[p];
        if (l == 0) wsh[w] = wt;
        if (wt != 0.f) {
            float x0 = corr[p * 2], x1 = corr[p * 2 + 1];
            h1[w][l]      = fmaxf(0.f, fmaf(x1, rel_w1[RELH + l],      fmaf(x0, rel_w1[l],      rel_b1[l])));
            h1[w][l + 64] = fmaxf(0.f, fmaf(x1, rel_w1[RELH + l + 64], fmaf(x0, rel_w1[l + 64], rel_b1[l + 64])));
        }
        __syncthreads();
        if (wsh[w] != 0.f) {
            float c0 = rel_b2[l], c1 = 0.f, c2 = 0.f, c3 = 0.f;
            const float4* hv = (const float4*)h1[w];
            #pragma unroll 8
            for (int k4 = 0; k4 < RELH / 4; ++k4) {
                float4 h = hv[k4];
                int k = k4 * 4;
                c0 = fmaf(h.x, rel_w2[k * R + l], c0);
                c1 = fmaf(h.y, rel_w2[(k + 1) * R + l], c1);
                c2 = fmaf(h.z, rel_w2[(k + 2) * R + l], c2);
                c3 = fmaf(h.w, rel_w2[(k + 3) * R + l], c3);
            }
            rs[w][l] = fmaxf(0.f, (c0 + c1) + (c2 + c3));
        }
        __syncthreads();
        #pragma unroll
        for (int ww = 0; ww < 4; ++ww) {
            float wtj = wsh[ww];
            if (wtj != 0.f) {
                int jj = j0 + ww;
                const float4* rv = (const float4*)rs[ww];
                float l0 = 0.f, l1 = 0.f, l2 = 0.f, l3 = 0.f;
                #pragma unroll 4
                for (int m4 = 0; m4 < R / 4; ++m4) {
                    float4 r4 = rv[m4];
                    int m = m4 * 4;
                    l0 = fmaf(r4.x, ngate_w[m * D + tid], l0);
                    l1 = fmaf(r4.y, ngate_w[(m + 1) * D + tid], l1);
                    l2 = fmaf(r4.z, ngate_w[(m + 2) * D + tid], l2);
                    l3 = fmaf(r4.w, ngate_w[(m + 3) * D + tid], l3);
                }
                float logit = base + Bm[jj * D + tid] + ((l0 + l1) + (l2 + l3));
                float g = fast_sigmoid(logit);
                acc = fmaf(wtj * self_h[jj * D + tid], g, acc);
            }
        }
        __syncthreads();
    }
    partial[(blockIdx.y * N + i) * D + tid] = acc;
}

// ---------------------------------------------------------------------------
// final_mfma: 24 blocks (16 rows) x 256 threads (4 waves). CHUNKS partials.
// ---------------------------------------------------------------------------
template<int CHUNKS>
__global__ __launch_bounds__(256, 2) void final_mfma_kernel(
        const float* __restrict__ partial,
        const _Float16* __restrict__ wf1, const _Float16* __restrict__ wf2,
        const float* __restrict__ wnei_b1, const float* __restrict__ wnei_b2,
        const float* __restrict__ self_c, const float* __restrict__ outgate,
        float* __restrict__ out) {
    __shared__ _Float16 hs16[16][HS_STRIDE];
    __shared__ _Float16 hid16[16][HS_STRIDE];
    int i0 = blockIdx.x * 16;
    int tid = threadIdx.x, wv = tid >> 6, l = tid & 63;
    int lg = l >> 4, ln = l & 15;

    #pragma unroll
    for (int s = 0; s < 4; ++s) {
        int f4 = tid + s * 256;
        int row = f4 >> 6, c4 = f4 & 63;
        float4 a = {0.f, 0.f, 0.f, 0.f};
        #pragma unroll
        for (int c = 0; c < CHUNKS; ++c) {
            float4 p = ((const float4*)partial)[(size_t)(c * N + i0 + row) * (D / 4) + c4];
            a.x += p.x; a.y += p.y; a.z += p.z; a.w += p.w;
        }
        hs16[row][c4 * 4 + 0] = (_Float16)a.x;
        hs16[row][c4 * 4 + 1] = (_Float16)a.y;
        hs16[row][c4 * 4 + 2] = (_Float16)a.z;
        hs16[row][c4 * 4 + 3] = (_Float16)a.w;
    }
    __syncthreads();

    {
        f32x4 c1[4];
        #pragma unroll
        for (int dt = 0; dt < 4; ++dt) c1[dt] = (f32x4){0.f, 0.f, 0.f, 0.f};
        #pragma unroll
        for (int s = 0; s < 8; ++s) {
            f16x8 a = *(const f16x8*)&hs16[ln][s * 32 + lg * 8];
            #pragma unroll
            for (int dt = 0; dt < 4; ++dt) {
                f16x8 bfv = *(const f16x8*)&wf1[((size_t)(s * 16 + wv * 4 + dt) * 64 + l) * 8];
                c1[dt] = __builtin_amdgcn_mfma_f32_16x16x32_f16(a, bfv, c1[dt], 0, 0, 0);
            }
        }
        #pragma unroll
        for (int dt = 0; dt < 4; ++dt) {
            int col = wv * 64 + dt * 16 + ln;
            float b1 = wnei_b1[col];
            #pragma unroll
            for (int reg = 0; reg < 4; ++reg)
                hid16[lg * 4 + reg][col] = (_Float16)fmaxf(0.f, c1[dt][reg] + b1);
        }
    }
    __syncthreads();

    {
        f32x4 c2[4];
        #pragma unroll
        for (int dt = 0; dt < 4; ++dt) c2[dt] = (f32x4){0.f, 0.f, 0.f, 0.f};
        #pragma unroll
        for (int s = 0; s < 8; ++s) {
            f16x8 a = *(const f16x8*)&hid16[ln][s * 32 + lg * 8];
            #pragma unroll
            for (int dt = 0; dt < 4; ++dt) {
                f16x8 bfv = *(const f16x8*)&wf2[((size_t)(s * 16 + wv * 4 + dt) * 64 + l) * 8];
                c2[dt] = __builtin_amdgcn_mfma_f32_16x16x32_f16(a, bfv, c2[dt], 0, 0, 0);
            }
        }
        #pragma unroll
        for (int dt = 0; dt < 4; ++dt) {
            int col = wv * 64 + dt * 16 + ln;
            float b2 = wnei_b2[col];
            #pragma unroll
            for (int reg = 0; reg < 4; ++reg) {
                int row = i0 + lg * 4 + reg;
                int idx = row * D + col;
                float C = c2[dt][reg] + b2 + self_c[idx];
                float og = outgate[idx];
                out[idx] = og;
                out[ND + idx] = og * fast_tanh(C);
                out[2 * ND + idx] = C;
            }
        }
    }
}

extern "C" void kernel_launch(void* const* d_in, const int* in_sizes, int n_in,
                              void* d_out, int out_size, void* d_ws, size_t ws_size,
                              hipStream_t stream) {
    const float* corr    = (const float*)d_in[0];
    const int*   nei     = (const int*)d_in[1];
    const float* outg    = (const float*)d_in[3];
    const float* self_h  = (const float*)d_in[4];
    const float* self_c  = (const float*)d_in[5];
    const float* rel_w1  = (const float*)d_in[6];
    const float* rel_b1  = (const float*)d_in[7];
    const float* rel_w2  = (const float*)d_in[8];
    const float* rel_b2  = (const float*)d_in[9];
    const float* ngate_w = (const float*)d_in[10];
    const float* ngate_b = (const float*)d_in[11];
    const float* war_w   = (const float*)d_in[12];
    const float* war_b   = (const float*)d_in[13];
    const float* wnei_w1 = (const float*)d_in[14];
    const float* wnei_b1 = (const float*)d_in[15];
    const float* wnei_w2 = (const float*)d_in[16];
    const float* wnei_b2 = (const float*)d_in[17];

    float* ws      = (float*)d_ws;
    float* tt      = ws;                       // NN (fallback only)
    float* pos     = ws + NN;                  // NN (fallback only)
    float* A       = ws + 2 * NN;              // ND (ngate_b prefolded)
    float* Bm      = ws + 2 * NN + ND;         // ND (fallback only)
    float* u       = ws + 2 * NN + 2 * ND;     // N
    float* v       = u + N;                    // N
    float* partial = v + N;                    // NCHUNK*ND (fused uses chunk 0)
    unsigned int* bh = (unsigned int*)(partial + NCHUNK * ND); // ND uints
    float* tail    = (float*)(bh + ND);
    _Float16* wf   = (_Float16*)tail;                   // 16384 fp16
    _Float16* wf1  = wf + 2 * 16 * 64 * 8;              // 65536 fp16
    _Float16* wf2  = wf1 + 8 * 16 * 64 * 8;             // 65536 fp16
    _Float16* wfr  = wf2 + 8 * 16 * 64 * 8;             // 8192 fp16
    size_t base_floats = (size_t)(2 * NN + 3 * ND + 2 * N + NCHUNK * ND);
    size_t f16_count = (size_t)(2 + 8 + 8) * 16 * 64 * 8 + 16 * 64 * 8;
    size_t need = (base_floats + f16_count / 2 + 16) * sizeof(float);
    bool use_fused = ws_size >= need;
    float* out = (float*)d_out;

    prep_kernel<<<79, 256, 0, stream>>>(self_h, ngate_w, ngate_b, war_w,
                                        wnei_w1, wnei_w2, rel_w2,
                                        A, Bm, bh, u, v, wf, wf1, wf2, wfr);
    if (use_fused) {
        fused_kernel<<<N, 256, 0, stream>>>(corr, rel_w1, rel_b1, rel_b2,
                                            war_w, v, nei, wfr, wf, A, bh, partial);
        final_mfma_kernel<1><<<N / 16, 256, 0, stream>>>(partial, wf1, wf2,
                                                         wnei_b1, wnei_b2,
                                                         self_c, outg, out);
    } else {
        tt_valu_kernel<<<NN / TPB, 256, 0, stream>>>(corr, rel_w1, rel_b1, rel_w2, rel_b2,
                                                     war_w, war_b, u, v, tt);
        softmax_kernel<<<N, 256, 0, stream>>>(tt, nei, pos);
        dim3 ggrid(N, NCHUNK);
        gate_norc_kernel<<<ggrid, 256, 0, stream>>>(corr, rel_w1, rel_b1, rel_w2, rel_b2,
                                                    ngate_w, A, Bm, pos, self_h,
                                                    partial);
        final_mfma_kernel<NCHUNK><<<N / 16, 256, 0, stream>>>(partial, wf1, wf2,
                                                              wnei_b1, wnei_b2,
                                                              self_c, outg, out);
    }
}

// Round 17
// 58.174 us; speedup vs baseline: 1.0365x; 1.0365x over previous
//
#include <hip/hip_runtime.h>
#include <hip/hip_bf16.h>
#include <math.h>

#define N 384
#define D 256
#define R 64
#define RELH 128
#define NN (N*N)
#define ND (N*D)
#define JCHUNK 64
#define NCHUNK (N / JCHUNK)   // 6
#define TPB 16                // legacy tt pairs per block (fallback)
#define LOG2E 1.44269504088896f
#define HS_STRIDE 264         // 256 + 8 fp16 pad

typedef _Float16 f16x8 __attribute__((ext_vector_type(8)));
typedef _Float16 f16x2 __attribute__((ext_vector_type(2)));
typedef float f32x4 __attribute__((ext_vector_type(4)));

__device__ __forceinline__ float fast_sigmoid(float x) {
    float e = __builtin_amdgcn_exp2f(-LOG2E * x);
    return __builtin_amdgcn_rcpf(1.f + e);
}
__device__ __forceinline__ float fast_exp(float x) {
    return __builtin_amdgcn_exp2f(LOG2E * x);
}
__device__ __forceinline__ float fast_tanh(float x) {
    float e = __builtin_amdgcn_exp2f(2.f * LOG2E * x);
    return 1.f - 2.f * __builtin_amdgcn_rcpf(1.f + e);
}

// ---------------------------------------------------------------------------
// prep_kernel: role-switched on blockIdx.x (79 blocks x 256 threads)
//  [0,6):   u/v wave reductions
//  [6,54):  [A+ngate_b | Bm] = self_h @ ngate_w[64:576] via fp16 MFMA;
//           Bm packed with self_h into bh (fp16x2)
//  [54,62): wf  = fragment-ordered fp16 ngate_w[0:64,:]
//  [62,78): wf1/wf2 = fragment-ordered fp16 wnei_w1 / wnei_w2
//  [78]:    wfr = fragment-ordered fp16 rel_w2 (128x64)
// ---------------------------------------------------------------------------
__global__ __launch_bounds__(256) void prep_kernel(
        const float* __restrict__ self_h, const float* __restrict__ ngate_w,
        const float* __restrict__ ngate_b, const float* __restrict__ war_w,
        const float* __restrict__ wnei_w1, const float* __restrict__ wnei_w2,
        const float* __restrict__ rel_w2,
        float* __restrict__ A, float* __restrict__ Bm,
        unsigned int* __restrict__ bh,
        float* __restrict__ u, float* __restrict__ v,
        _Float16* __restrict__ wf,
        _Float16* __restrict__ wf1, _Float16* __restrict__ wf2,
        _Float16* __restrict__ wfr) {
    int b = blockIdx.x, tid = threadIdx.x;
    int wv = tid >> 6, l = tid & 63;
    int lg = l >> 4, ln = l & 15;

    if (b < 6) {
        int r0 = b * 64 + wv * 16;
        for (int rr = 0; rr < 16; ++rr) {
            int row = r0 + rr;
            float su = 0.f, sv = 0.f;
            #pragma unroll
            for (int k = 0; k < 4; ++k) {
                int d = k * 64 + l;
                float h = self_h[row * D + d];
                su = fmaf(h, war_w[R + d], su);
                sv = fmaf(h, war_w[R + D + d], sv);
            }
            #pragma unroll
            for (int off = 32; off; off >>= 1) {
                su += __shfl_down(su, off);
                sv += __shfl_down(sv, off);
            }
            if (l == 0) { u[row] = su; v[row] = sv; }
        }
    } else if (b < 54) {
        int W = (b - 6) * 4 + wv;        // 0..191
        int m0 = (W >> 3) * 16;          // row block
        int cb = (W & 7) * 64;           // col base in [0,512)
        const float* wsrc = ngate_w + (size_t)(cb >= 256 ? 320 : 64) * D + (cb & 255);
        f32x4 acc[4];
        #pragma unroll
        for (int nt = 0; nt < 4; ++nt) acc[nt] = (f32x4){0.f, 0.f, 0.f, 0.f};
        #pragma unroll
        for (int s = 0; s < 8; ++s) {
            const float4* hp = (const float4*)&self_h[(size_t)(m0 + ln) * D + s * 32 + lg * 8];
            float4 h0 = hp[0], h1 = hp[1];
            f16x8 af;
            af[0] = (_Float16)h0.x; af[1] = (_Float16)h0.y;
            af[2] = (_Float16)h0.z; af[3] = (_Float16)h0.w;
            af[4] = (_Float16)h1.x; af[5] = (_Float16)h1.y;
            af[6] = (_Float16)h1.z; af[7] = (_Float16)h1.w;
            #pragma unroll
            for (int nt = 0; nt < 4; ++nt) {
                f16x8 bf;
                #pragma unroll
                for (int ii = 0; ii < 8; ++ii)
                    bf[ii] = (_Float16)wsrc[(size_t)(s * 32 + lg * 8 + ii) * D + nt * 16 + ln];
                acc[nt] = __builtin_amdgcn_mfma_f32_16x16x32_f16(af, bf, acc[nt], 0, 0, 0);
            }
        }
        #pragma unroll
        for (int nt = 0; nt < 4; ++nt)
            #pragma unroll
            for (int reg = 0; reg < 4; ++reg) {
                int row = m0 + lg * 4 + reg;
                int col = cb + nt * 16 + ln;
                if (col < 256) {
                    A[row * D + col] = acc[nt][reg] + ngate_b[col];
                } else {
                    int c2 = col - 256;
                    float bmv = acc[nt][reg];
                    Bm[row * D + c2] = bmv;                 // fallback path
                    f16x2 pk;
                    pk[0] = (_Float16)bmv;
                    pk[1] = (_Float16)self_h[row * D + c2];
                    bh[row * D + c2] = __builtin_bit_cast(unsigned int, pk);
                }
            }
    } else if (b < 62) {
        int blkEq = (b - 54) * 4 + wv;   // 0..31
        int s = blkEq >> 4, t = blkEq & 15;
        #pragma unroll
        for (int ii = 0; ii < 8; ++ii) {
            float w = ngate_w[(s * 32 + lg * 8 + ii) * D + t * 16 + ln];
            wf[((size_t)(s * 16 + t) * 64 + l) * 8 + ii] = (_Float16)w;
        }
    } else if (b < 78) {
        int base = ((b - 62) * 4 + wv) * 4;   // tile base in [0,256)
        #pragma unroll
        for (int k = 0; k < 4; ++k) {
            int T = base + k;
            int mat = T >> 7, rem = T & 127;
            int s = rem >> 4, t = rem & 15;
            const float* wsrc = mat ? wnei_w2 : wnei_w1;
            _Float16* dst = mat ? wf2 : wf1;
            #pragma unroll
            for (int ii = 0; ii < 8; ++ii) {
                float w = wsrc[(size_t)(s * 32 + lg * 8 + ii) * D + t * 16 + ln];
                dst[((size_t)(s * 16 + t) * 64 + l) * 8 + ii] = (_Float16)w;
            }
        }
    } else {
        // wfr: rel_w2 [128x64] fragments; 16 tiles (s 0..3, nt 0..3)
        #pragma unroll
        for (int k = 0; k < 4; ++k) {
            int T = wv * 4 + k;
            int s = T >> 2, nt = T & 3;
            #pragma unroll
            for (int ii = 0; ii < 8; ++ii) {
                float w = rel_w2[(size_t)(s * 32 + lg * 8 + ii) * R + nt * 16 + ln];
                wfr[((size_t)(s * 4 + nt) * 64 + l) * 8 + ii] = (_Float16)w;
            }
        }
    }
}

// ---------------------------------------------------------------------------
// fused_kernel: one block per row i, 256 threads = 4 waves.
// Phase 1: rel-MLP r for all 384 j via MFMA -> fp16 LDS (XOR-swizzled);
//          war-logit (r.war_w + v[j]) -> ttrow LDS.
// Phase 2: in-block masked softmax -> pos (reuses ttrow).
// Phase 3: wave wv owns d in [wv*64,(wv+1)*64): logits via MFMA (A from LDS,
//          B=wf), sigmoid epilogue with bh from L2, accumulate over ALL j,
//          write hsum[i] directly.
// ---------------------------------------------------------------------------
__global__ __launch_bounds__(256) void fused_kernel(
        const float* __restrict__ corr,
        const float* __restrict__ rel_w1, const float* __restrict__ rel_b1,
        const float* __restrict__ rel_b2,
        const float* __restrict__ war_w, const float* __restrict__ v,
        const int* __restrict__ nei,
        const _Float16* __restrict__ wfr, const _Float16* __restrict__ wf,
        const float* __restrict__ A, const unsigned int* __restrict__ bh,
        float* __restrict__ hsum) {
    __shared__ __align__(16) _Float16 rlds[N * R];   // 48 KB, swizzled
    __shared__ float ttrow[N];
    __shared__ float red[4];
    __shared__ float sM, sS;
    int i = blockIdx.x, tid = threadIdx.x;
    int wv = tid >> 6, l = tid & 63;
    int lg = l >> 4, ln = l & 15;
    char* rbase = (char*)rlds;

    // ---- phase 1 ----
    float w10[4][8], w11[4][8], b1v[4][8];
    #pragma unroll
    for (int s = 0; s < 4; ++s)
        #pragma unroll
        for (int ii = 0; ii < 8; ++ii) {
            int hk = s * 32 + lg * 8 + ii;
            w10[s][ii] = rel_w1[hk];
            w11[s][ii] = rel_w1[RELH + hk];
            b1v[s][ii] = rel_b1[hk];
        }
    float b2r[4], warw[4];
    #pragma unroll
    for (int nt = 0; nt < 4; ++nt) {
        b2r[nt]  = rel_b2[nt * 16 + ln];
        warw[nt] = war_w[nt * 16 + ln];
    }

    #pragma unroll
    for (int t = 0; t < 6; ++t) {
        int j0 = (wv * 6 + t) * 16;
        float2 x = ((const float2*)corr)[(size_t)i * N + j0 + ln];
        f16x8 af[4];
        #pragma unroll
        for (int s = 0; s < 4; ++s)
            #pragma unroll
            for (int ii = 0; ii < 8; ++ii) {
                float h = fmaxf(0.f, fmaf(x.y, w11[s][ii], fmaf(x.x, w10[s][ii], b1v[s][ii])));
                af[s][ii] = (_Float16)h;
            }
        f32x4 c[4];
        #pragma unroll
        for (int nt = 0; nt < 4; ++nt) c[nt] = (f32x4){0.f, 0.f, 0.f, 0.f};
        #pragma unroll
        for (int nt = 0; nt < 4; ++nt)
            #pragma unroll
            for (int s = 0; s < 4; ++s) {
                f16x8 bfv = *(const f16x8*)&wfr[((size_t)(s * 4 + nt) * 64 + l) * 8];
                c[nt] = __builtin_amdgcn_mfma_f32_16x16x32_f16(af[s], bfv, c[nt], 0, 0, 0);
            }
        float tpart[4] = {0.f, 0.f, 0.f, 0.f};
        #pragma unroll
        for (int nt = 0; nt < 4; ++nt)
            #pragma unroll
            for (int reg = 0; reg < 4; ++reg) {
                float rv = fmaxf(0.f, c[nt][reg] + b2r[nt]);
                int j = j0 + lg * 4 + reg;
                int off = (j * 128 + (nt * 16 + ln) * 2) ^ ((j & 7) << 4);
                *(_Float16*)(rbase + off) = (_Float16)rv;
                tpart[reg] = fmaf(rv, warw[nt], tpart[reg]);
            }
        #pragma unroll
        for (int reg = 0; reg < 4; ++reg) {
            float tsum = tpart[reg];
            #pragma unroll
            for (int off = 8; off; off >>= 1) tsum += __shfl_xor(tsum, off, 16);
            tpart[reg] = tsum;
        }
        if (ln == 0) {
            #pragma unroll
            for (int reg = 0; reg < 4; ++reg) {
                int j = j0 + lg * 4 + reg;
                ttrow[j] = tpart[reg] + v[j];
            }
        }
    }
    __syncthreads();

    // ---- phase 2: softmax over ttrow[0..383] ----
    {
        float tv1 = ttrow[tid];
        bool va1 = (nei[(size_t)i * N + tid] > 0) && (tv1 != 0.f);
        float tv2 = 0.f; bool va2 = false;
        if (tid < N - 256) {
            tv2 = ttrow[tid + 256];
            va2 = (nei[(size_t)i * N + tid + 256] > 0) && (tv2 != 0.f);
        }
        float m = va1 ? tv1 : -INFINITY;
        if (va2) m = fmaxf(m, tv2);
        #pragma unroll
        for (int off = 32; off; off >>= 1) m = fmaxf(m, __shfl_down(m, off));
        if (l == 0) red[wv] = m;
        __syncthreads();
        if (tid == 0) sM = fmaxf(fmaxf(red[0], red[1]), fmaxf(red[2], red[3]));
        __syncthreads();
        float M = sM;
        float e1 = 0.f, e2 = 0.f;
        if (M != -INFINITY) {
            if (va1) e1 = fast_exp(tv1 - M);
            if (va2) e2 = fast_exp(tv2 - M);
        }
        float sum = e1 + e2;
        #pragma unroll
        for (int off = 32; off; off >>= 1) sum += __shfl_down(sum, off);
        if (l == 0) red[wv] = sum;
        __syncthreads();
        if (tid == 0) sS = red[0] + red[1] + red[2] + red[3];
        __syncthreads();
        float rden = (sS > 0.f) ? __builtin_amdgcn_rcpf(sS) : 0.f;
        ttrow[tid] = va1 ? e1 * rden : 0.f;
        if (tid < N - 256) ttrow[tid + 256] = va2 ? e2 * rden : 0.f;
    }
    __syncthreads();

    // ---- phase 3: gate over all j for this wave's 64 d-cols ----
    f16x8 bf[2][4];
    #pragma unroll
    for (int s = 0; s < 2; ++s)
        #pragma unroll
        for (int dt = 0; dt < 4; ++dt)
            bf[s][dt] = *(const f16x8*)&wf[((size_t)(s * 16 + wv * 4 + dt) * 64 + l) * 8];
    float based[4];
    #pragma unroll
    for (int dt = 0; dt < 4; ++dt)
        based[dt] = A[i * D + wv * 64 + dt * 16 + ln];

    float acc[4] = {0.f, 0.f, 0.f, 0.f};
    for (int jt = 0; jt < 24; ++jt) {
        int jb = jt * 16;
        f16x8 afr[2];
        #pragma unroll
        for (int s = 0; s < 2; ++s) {
            int j = jb + ln;
            int off = (j * 128 + (s * 64 + lg * 16)) ^ ((j & 7) << 4);
            afr[s] = *(const f16x8*)(rbase + off);
        }
        f32x4 c[4];
        #pragma unroll
        for (int dt = 0; dt < 4; ++dt) c[dt] = (f32x4){0.f, 0.f, 0.f, 0.f};
        #pragma unroll
        for (int dt = 0; dt < 4; ++dt)
            #pragma unroll
            for (int s = 0; s < 2; ++s)
                c[dt] = __builtin_amdgcn_mfma_f32_16x16x32_f16(afr[s], bf[s][dt], c[dt], 0, 0, 0);
        #pragma unroll
        for (int reg = 0; reg < 4; ++reg) {
            int jj = jb + lg * 4 + reg;
            float p = ttrow[jj];
            #pragma unroll
            for (int dt = 0; dt < 4; ++dt) {
                int d = wv * 64 + dt * 16 + ln;
                unsigned int uu = bh[(size_t)jj * D + d];
                f16x2 bhv = __builtin_bit_cast(f16x2, uu);
                float logit = c[dt][reg] + based[dt] + (float)bhv[0];
                float g = fast_sigmoid(logit);
                acc[dt] = fmaf(p * g, (float)bhv[1], acc[dt]);
            }
        }
    }
    #pragma unroll
    for (int dt = 0; dt < 4; ++dt) {
        float a = acc[dt];
        a += __shfl_xor(a, 16);
        a += __shfl_xor(a, 32);
        acc[dt] = a;
    }
    if (lg == 0) {
        #pragma unroll
        for (int dt = 0; dt < 4; ++dt)
            hsum[(size_t)i * D + wv * 64 + dt * 16 + ln] = acc[dt];
    }
}

// ---------------------------------------------------------------------------
// Fallback VALU tt.
// ---------------------------------------------------------------------------
__global__ __launch_bounds__(256) void tt_valu_kernel(
        const float* __restrict__ corr,
        const float* __restrict__ rel_w1, const float* __restrict__ rel_b1,
        const float* __restrict__ rel_w2, const float* __restrict__ rel_b2,
        const float* __restrict__ war_w, const float* __restrict__ war_b,
        const float* __restrict__ u, const float* __restrict__ v,
        float* __restrict__ tt) {
    __shared__ __align__(16) float h1s[4][RELH];
    int tid = threadIdx.x, w = tid >> 6, l = tid & 63;
    float w1a0 = rel_w1[l],      w1a1 = rel_w1[RELH + l];
    float w1b0 = rel_w1[64 + l], w1b1 = rel_w1[RELH + 64 + l];
    float b1a = rel_b1[l], b1b = rel_b1[64 + l];
    float b2v = rel_b2[l], warw = war_w[l], wb = war_b[0];
    int pbase = blockIdx.x * TPB;
    #pragma unroll
    for (int it = 0; it < TPB / 4; ++it) {
        int p = pbase + it * 4 + w;
        int i = p / N, j = p - i * N;
        float2 x = *(const float2*)(corr + p * 2);
        h1s[w][l]      = fmaxf(0.f, fmaf(x.y, w1a1, fmaf(x.x, w1a0, b1a)));
        h1s[w][l + 64] = fmaxf(0.f, fmaf(x.y, w1b1, fmaf(x.x, w1b0, b1b)));
        float c0 = b2v, c1 = 0.f, c2 = 0.f, c3 = 0.f;
        const float4* hv = (const float4*)h1s[w];
        #pragma unroll
        for (int k4 = 0; k4 < RELH / 4; ++k4) {
            float4 h = hv[k4];
            c0 = fmaf(h.x, rel_w2[(k4 * 4 + 0) * R + l], c0);
            c1 = fmaf(h.y, rel_w2[(k4 * 4 + 1) * R + l], c1);
            c2 = fmaf(h.z, rel_w2[(k4 * 4 + 2) * R + l], c2);
            c3 = fmaf(h.w, rel_w2[(k4 * 4 + 3) * R + l], c3);
        }
        float rm = fmaxf(0.f, (c0 + c1) + (c2 + c3));
        float part = rm * warw;
        for (int off = 32; off; off >>= 1) part += __shfl_down(part, off);
        if (l == 0) tt[p] = part + u[i] + v[j] + wb;
    }
}

// ---------------------------------------------------------------------------
// Fallback row softmax.
// ---------------------------------------------------------------------------
__global__ void softmax_kernel(const float* __restrict__ tt,
                               const int* __restrict__ nei,
                               float* __restrict__ pos) {
    __shared__ float red[4];
    __shared__ float sM, sS;
    int i = blockIdx.x, tid = threadIdx.x;
    float tv[2]; bool valid[2];
    float m = -INFINITY;
    for (int s = 0; s < 2; ++s) {
        int j = tid + s * 256;
        valid[s] = false; tv[s] = 0.f;
        if (j < N) {
            float t = tt[i * N + j];
            bool va = (nei[i * N + j] > 0) && (t != 0.f);
            tv[s] = t; valid[s] = va;
            if (va) m = fmaxf(m, t);
        }
    }
    for (int off = 32; off; off >>= 1) m = fmaxf(m, __shfl_down(m, off));
    if ((tid & 63) == 0) red[tid >> 6] = m;
    __syncthreads();
    if (tid == 0) sM = fmaxf(fmaxf(red[0], red[1]), fmaxf(red[2], red[3]));
    __syncthreads();
    float M = sM;
    float e[2] = {0.f, 0.f};
    float sum = 0.f;
    if (M != -INFINITY) {
        for (int s = 0; s < 2; ++s)
            if (valid[s]) { e[s] = fast_exp(tv[s] - M); sum += e[s]; }
    }
    for (int off = 32; off; off >>= 1) sum += __shfl_down(sum, off);
    if ((tid & 63) == 0) red[tid >> 6] = sum;
    __syncthreads();
    if (tid == 0) sS = red[0] + red[1] + red[2] + red[3];
    __syncthreads();
    float rden = (sS > 0.f) ? __builtin_amdgcn_rcpf(sS) : 0.f;
    for (int s = 0; s < 2; ++s) {
        int j = tid + s * 256;
        if (j < N) pos[i * N + j] = valid[s] ? e[s] * rden : 0.f;
    }
}

// ---------------------------------------------------------------------------
// Fallback gate (no workspace for fused path).
// ---------------------------------------------------------------------------
__global__ void gate_norc_kernel(const float* __restrict__ corr,
                            const float* __restrict__ rel_w1, const float* __restrict__ rel_b1,
                            const float* __restrict__ rel_w2, const float* __restrict__ rel_b2,
                            const float* __restrict__ ngate_w,
                            const float* __restrict__ A, const float* __restrict__ Bm,
                            const float* __restrict__ pos, const float* __restrict__ self_h,
                            float* __restrict__ partial) {
    __shared__ __align__(16) float h1[4][RELH];
    __shared__ __align__(16) float rs[4][R];
    __shared__ float wsh[4];
    int i = blockIdx.x, tid = threadIdx.x;
    int jbase = blockIdx.y * JCHUNK;
    int w = tid >> 6, l = tid & 63;
    ((float*)rs)[tid] = 0.f;
    float base = A[i * D + tid];
    float acc = 0.f;
    for (int j0 = jbase; j0 < jbase + JCHUNK; j0 += 4) {
        int j = j0 + w;
        int p = i * N + j;
        float wt = pos[p];
        if (l == 0) wsh[w] = wt;
        if (wt != 0.f) {
            float x0 = corr[p * 2], x1 = corr[p * 2 + 1];
            h1[w][l]      = fmaxf(0.f, fmaf(x1, rel_w1[RELH + l],      fmaf(x0, rel_w1[l],      rel_b1[l])));
            h1[w][l + 64] = fmaxf(0.f, fmaf(x1, rel_w1[RELH + l + 64], fmaf(x0, rel_w1[l + 64], rel_b1[l + 64])));
        }
        __syncthreads();
        if (wsh[w] != 0.f) {
            float c0 = rel_b2[l], c1 = 0.f, c2 = 0.f, c3 = 0.f;
            const float4* hv = (const float4*)h1[w];
            #pragma unroll 8
            for (int k4 = 0; k4 < RELH / 4; ++k4) {
                float4 h = hv[k4];
                int k = k4 * 4;
                c0 = fmaf(h.x, rel_w2[k * R + l], c0);
                c1 = fmaf(h.y, rel_w2[(k + 1) * R + l], c1);
                c2 = fmaf(h.z, rel_w2[(k + 2) * R + l], c2);
                c3 = fmaf(h.w, rel_w2[(k + 3) * R + l], c3);
            }
            rs[w][l] = fmaxf(0.f, (c0 + c1) + (c2 + c3));
        }
        __syncthreads();
        #pragma unroll
        for (int ww = 0; ww < 4; ++ww) {
            float wtj = wsh[ww];
            if (wtj != 0.f) {
                int jj = j0 + ww;
                const float4* rv = (const float4*)rs[ww];
                float l0 = 0.f, l1 = 0.f, l2 = 0.f, l3 = 0.f;
                #pragma unroll 4
                for (int m4 = 0; m4 < R / 4; ++m4) {
                    float4 r4 = rv[m4];
                    int m = m4 * 4;
                    l0 = fmaf(r4.x, ngate_w[m * D + tid], l0);
                    l1 = fmaf(r4.y, ngate_w[(m + 1) * D + tid], l1);
                    l2 = fmaf(r4.z, ngate_w[(m + 2) * D + tid], l2);
                    l3 = fmaf(r4.w, ngate_w[(m + 3) * D + tid], l3);
                }
                float logit = base + Bm[jj * D + tid] + ((l0 + l1) + (l2 + l3));
                float g = fast_sigmoid(logit);
                acc = fmaf(wtj * self_h[jj * D + tid], g, acc);
            }
        }
        __syncthreads();
    }
    partial[(blockIdx.y * N + i) * D + tid] = acc;
}

// ---------------------------------------------------------------------------
// final_mfma: 24 blocks (16 rows) x 256 threads (4 waves). CHUNKS partials.
// ---------------------------------------------------------------------------
template<int CHUNKS>
__global__ __launch_bounds__(256, 2) void final_mfma_kernel(
        const float* __restrict__ partial,
        const _Float16* __restrict__ wf1, const _Float16* __restrict__ wf2,
        const float* __restrict__ wnei_b1, const float* __restrict__ wnei_b2,
        const float* __restrict__ self_c, const float* __restrict__ outgate,
        float* __restrict__ out) {
    __shared__ _Float16 hs16[16][HS_STRIDE];
    __shared__ _Float16 hid16[16][HS_STRIDE];
    int i0 = blockIdx.x * 16;
    int tid = threadIdx.x, wv = tid >> 6, l = tid & 63;
    int lg = l >> 4, ln = l & 15;

    #pragma unroll
    for (int s = 0; s < 4; ++s) {
        int f4 = tid + s * 256;
        int row = f4 >> 6, c4 = f4 & 63;
        float4 a = {0.f, 0.f, 0.f, 0.f};
        #pragma unroll
        for (int c = 0; c < CHUNKS; ++c) {
            float4 p = ((const float4*)partial)[(size_t)(c * N + i0 + row) * (D / 4) + c4];
            a.x += p.x; a.y += p.y; a.z += p.z; a.w += p.w;
        }
        hs16[row][c4 * 4 + 0] = (_Float16)a.x;
        hs16[row][c4 * 4 + 1] = (_Float16)a.y;
        hs16[row][c4 * 4 + 2] = (_Float16)a.z;
        hs16[row][c4 * 4 + 3] = (_Float16)a.w;
    }
    __syncthreads();

    {
        f32x4 c1[4];
        #pragma unroll
        for (int dt = 0; dt < 4; ++dt) c1[dt] = (f32x4){0.f, 0.f, 0.f, 0.f};
        #pragma unroll
        for (int s = 0; s < 8; ++s) {
            f16x8 a = *(const f16x8*)&hs16[ln][s * 32 + lg * 8];
            #pragma unroll
            for (int dt = 0; dt < 4; ++dt) {
                f16x8 bfv = *(const f16x8*)&wf1[((size_t)(s * 16 + wv * 4 + dt) * 64 + l) * 8];
                c1[dt] = __builtin_amdgcn_mfma_f32_16x16x32_f16(a, bfv, c1[dt], 0, 0, 0);
            }
        }
        #pragma unroll
        for (int dt = 0; dt < 4; ++dt) {
            int col = wv * 64 + dt * 16 + ln;
            float b1 = wnei_b1[col];
            #pragma unroll
            for (int reg = 0; reg < 4; ++reg)
                hid16[lg * 4 + reg][col] = (_Float16)fmaxf(0.f, c1[dt][reg] + b1);
        }
    }
    __syncthreads();

    {
        f32x4 c2[4];
        #pragma unroll
        for (int dt = 0; dt < 4; ++dt) c2[dt] = (f32x4){0.f, 0.f, 0.f, 0.f};
        #pragma unroll
        for (int s = 0; s < 8; ++s) {
            f16x8 a = *(const f16x8*)&hid16[ln][s * 32 + lg * 8];
            #pragma unroll
            for (int dt = 0; dt < 4; ++dt) {
                f16x8 bfv = *(const f16x8*)&wf2[((size_t)(s * 16 + wv * 4 + dt) * 64 + l) * 8];
                c2[dt] = __builtin_amdgcn_mfma_f32_16x16x32_f16(a, bfv, c2[dt], 0, 0, 0);
            }
        }
        #pragma unroll
        for (int dt = 0; dt < 4; ++dt) {
            int col = wv * 64 + dt * 16 + ln;
            float b2 = wnei_b2[col];
            #pragma unroll
            for (int reg = 0; reg < 4; ++reg) {
                int row = i0 + lg * 4 + reg;
                int idx = row * D + col;
                float C = c2[dt][reg] + b2 + self_c[idx];
                float og = outgate[idx];
                out[idx] = og;
                out[ND + idx] = og * fast_tanh(C);
                out[2 * ND + idx] = C;
            }
        }
    }
}

extern "C" void kernel_launch(void* const* d_in, const int* in_sizes, int n_in,
                              void* d_out, int out_size, void* d_ws, size_t ws_size,
                              hipStream_t stream) {
    const float* corr    = (const float*)d_in[0];
    const int*   nei     = (const int*)d_in[1];
    const float* outg    = (const float*)d_in[3];
    const float* self_h  = (const float*)d_in[4];
    const float* self_c  = (const float*)d_in[5];
    const float* rel_w1  = (const float*)d_in[6];
    const float* rel_b1  = (const float*)d_in[7];
    const float* rel_w2  = (const float*)d_in[8];
    const float* rel_b2  = (const float*)d_in[9];
    const float* ngate_w = (const float*)d_in[10];
    const float* ngate_b = (const float*)d_in[11];
    const float* war_w   = (const float*)d_in[12];
    const float* war_b   = (const float*)d_in[13];
    const float* wnei_w1 = (const float*)d_in[14];
    const float* wnei_b1 = (const float*)d_in[15];
    const float* wnei_w2 = (const float*)d_in[16];
    const float* wnei_b2 = (const float*)d_in[17];

    float* ws      = (float*)d_ws;
    float* tt      = ws;                       // NN (fallback only)
    float* pos     = ws + NN;                  // NN (fallback only)
    float* A       = ws + 2 * NN;              // ND (ngate_b prefolded)
    float* Bm      = ws + 2 * NN + ND;         // ND (fallback only)
    float* u       = ws + 2 * NN + 2 * ND;     // N
    float* v       = u + N;                    // N
    float* partial = v + N;                    // NCHUNK*ND (fused uses chunk 0)
    unsigned int* bh = (unsigned int*)(partial + NCHUNK * ND); // ND uints
    float* tail    = (float*)(bh + ND);
    _Float16* wf   = (_Float16*)tail;                   // 16384 fp16
    _Float16* wf1  = wf + 2 * 16 * 64 * 8;              // 65536 fp16
    _Float16* wf2  = wf1 + 8 * 16 * 64 * 8;             // 65536 fp16
    _Float16* wfr  = wf2 + 8 * 16 * 64 * 8;             // 8192 fp16
    size_t base_floats = (size_t)(2 * NN + 3 * ND + 2 * N + NCHUNK * ND);
    size_t f16_count = (size_t)(2 + 8 + 8) * 16 * 64 * 8 + 16 * 64 * 8;
    size_t need = (base_floats + f16_count / 2 + 16) * sizeof(float);
    bool use_fused = ws_size >= need;
    float* out = (float*)d_out;

    prep_kernel<<<79, 256, 0, stream>>>(self_h, ngate_w, ngate_b, war_w,
                                        wnei_w1, wnei_w2, rel_w2,
                                        A, Bm, bh, u, v, wf, wf1, wf2, wfr);
    if (use_fused) {
        fused_kernel<<<N, 256, 0, stream>>>(corr, rel_w1, rel_b1, rel_b2,
                                            war_w, v, nei, wfr, wf, A, bh, partial);
        final_mfma_kernel<1><<<N / 16, 256, 0, stream>>>(partial, wf1, wf2,
                                                         wnei_b1, wnei_b2,
                                                         self_c, outg, out);
    } else {
        tt_valu_kernel<<<NN / TPB, 256, 0, stream>>>(corr, rel_w1, rel_b1, rel_w2, rel_b2,
                                                     war_w, war_b, u, v, tt);
        softmax_kernel<<<N, 256, 0, stream>>>(tt, nei, pos);
        dim3 ggrid(N, NCHUNK);
        gate_norc_kernel<<<ggrid, 256, 0, stream>>>(corr, rel_w1, rel_b1, rel_w2, rel_b2,
                                                    ngate_w, A, Bm, pos, self_h,
                                                    partial);
        final_mfma_kernel<NCHUNK><<<N / 16, 256, 0, stream>>>(partial, wf1, wf2,
                                                              wnei_b1, wnei_b2,
                                                              self_c, outg, out);
    }
}